// Round 8
// baseline (342.973 us; speedup 1.0000x reference)
//
#include <hip/hip_runtime.h>
#include <math.h>

#define Vn 5
#define Cn 32
#define Hn 384
#define Wn 384
#define Dn 4
#define Gn 8
#define HWn (Hn*Wn)   // 147456

typedef _Float16 h2 __attribute__((ext_vector_type(2)));

__device__ __forceinline__ float fdot2h(h2 a, h2 b, float c){
#if __has_builtin(__builtin_amdgcn_fdot2)
    return __builtin_amdgcn_fdot2(a, b, c, false);
#else
    return (float)a.x*(float)b.x + (float)a.y*(float)b.y + c;
#endif
}
__device__ __forceinline__ unsigned int packh2(float a, float b){  // accurate pack (RNE)
    h2 h;
    h.x = (_Float16)a;
    h.y = (_Float16)b;
    return __builtin_bit_cast(unsigned int, h);
}

// ---------- small 3x3 helpers (device) ----------
__device__ __forceinline__ void inv3(const float* m, float* o){
    float a=m[0],b=m[1],c=m[2],d=m[3],e=m[4],f=m[5],g=m[6],h=m[7],i=m[8];
    float A =  e*i - f*h;
    float B = -(d*i - f*g);
    float C =  d*h - e*g;
    float det = a*A + b*B + c*C;
    float r = 1.f/det;
    o[0] = A*r;            o[1] = -(b*i - c*h)*r;  o[2] =  (b*f - c*e)*r;
    o[3] = B*r;            o[4] =  (a*i - c*g)*r;  o[5] = -(a*f - c*d)*r;
    o[6] = C*r;            o[7] = -(a*h - b*g)*r;  o[8] =  (a*e - b*d)*r;
}
__device__ __forceinline__ void mm3(const float* a, const float* b, float* o){
    #pragma unroll
    for (int r=0;r<3;r++)
        #pragma unroll
        for (int c=0;c<3;c++)
            o[r*3+c] = a[r*3+0]*b[0*3+c] + a[r*3+1]*b[1*3+c] + a[r*3+2]*b[2*3+c];
}
__device__ __forceinline__ void mv3(const float* a, const float* v, float* o){
    #pragma unroll
    for (int r=0;r<3;r++)
        o[r] = a[r*3+0]*v[0] + a[r*3+1]*v[1] + a[r*3+2]*v[2];
}

// ---------- transpose+convert source views (C,H,W) fp32 -> (H*W, C) f16 ----------
__global__ __launch_bounds__(256)
void transpose_kernel(const float* __restrict__ feat, unsigned short* __restrict__ featT){
    __shared__ float tile[32][257];
    const int s  = blockIdx.y;            // 0..3 -> view s+1
    const int p0 = blockIdx.x * 256;      // pixel tile base
    const int t  = threadIdx.x;
    const float* src = feat + (size_t)(s+1)*Cn*HWn + p0;
    #pragma unroll
    for (int k=0;k<8;k++){
        const int i   = k*256 + t;
        const int px4 = (i & 63) * 4;
        const int ch  = i >> 6;
        const float4 v = *(const float4*)(src + (size_t)ch*HWn + px4);
        tile[ch][px4+0]=v.x; tile[ch][px4+1]=v.y; tile[ch][px4+2]=v.z; tile[ch][px4+3]=v.w;
    }
    __syncthreads();
    uint4* dst = (uint4*)(featT + ((size_t)s*HWn + p0 + t)*Cn);
    #pragma unroll
    for (int q=0;q<4;q++){
        uint4 o;
        o.x = packh2(tile[8*q+0][t], tile[8*q+1][t]);
        o.y = packh2(tile[8*q+2][t], tile[8*q+3][t]);
        o.z = packh2(tile[8*q+4][t], tile[8*q+5][t]);
        o.w = packh2(tile[8*q+6][t], tile[8*q+7][t]);
        dst[q] = o;
    }
}

// one group (4 ch = 2 half2): two v_dot2_f32_f16 + one fma
#define DOTG(uA, uB, g)                                                        \
    {                                                                          \
        const h2 pa = __builtin_bit_cast(h2, (uA));                            \
        const h2 pb = __builtin_bit_cast(h2, (uB));                            \
        const float dt = fdot2h(pa, r2[2*(g)], fdot2h(pb, r2[2*(g)+1], 0.f));  \
        sg[(g)] = fmaf(w, dt, sg[(g)]);                                        \
    }

// guarded bilinear tap: loads only if weight nonzero, immediate consume
__device__ __forceinline__ void tap_f16(const unsigned short* __restrict__ vbase,
                                        int xc, int yc, float w,
                                        const h2* r2, float* sg)
{
    if (w != 0.f){
        const uint4* p = (const uint4*)(vbase + ((size_t)yc*Wn + xc)*Cn);
        const uint4 q0 = p[0];
        const uint4 q1 = p[1];
        const uint4 q2 = p[2];
        const uint4 q3 = p[3];
        DOTG(q0.x, q0.y, 0)
        DOTG(q0.z, q0.w, 1)
        DOTG(q1.x, q1.y, 2)
        DOTG(q1.z, q1.w, 3)
        DOTG(q2.x, q2.y, 4)
        DOTG(q2.z, q2.w, 5)
        DOTG(q3.x, q3.y, 6)
        DOTG(q3.z, q3.w, 7)
    }
}

// ---------- fused main kernel: one thread per (pixel, source view) ----------
// Block = 256 threads = 64 pixels x 4 views; 4 view-lanes adjacent -> shfl_xor.
// launch_bounds(256,2): empirical VGPR cap 128 (cap 64 at arg=4 caused 1.6GB
// of scratch spill traffic in R4 -- this kernel needs ~100 VGPRs).
__global__ __launch_bounds__(256, 2)
void gbinet_kernel(const float* __restrict__ feat,
                   const float* __restrict__ depths,
                   const float* __restrict__ Kin,
                   const float* __restrict__ Ein,
                   const float* __restrict__ w0, const float* __restrict__ b0,
                   const float* __restrict__ w1, const float* __restrict__ b1,
                   const float* __restrict__ w2, const float* __restrict__ b2,
                   const unsigned short* __restrict__ featT,
                   float* __restrict__ out)
{
    __shared__ float sW0[128], sW1[128], sB0[16], sB1[8], sW2[8], sB2s[1];
    __shared__ float sM[48];            // per source view: A[9] + c[3]
    __shared__ float sRef[64*33];       // 64 pixels x 32 ref channels (pad 33)
    __shared__ float sDep[4*65];        // 4 depth planes x 64 pixels (pad 65)
    __shared__ float sOut[64*33];       // 64 pixels x 32 outputs (pad 33)
    const int t = threadIdx.x;
    if (t < 128){ sW0[t] = w0[t]; sW1[t] = w1[t]; }
    if (t < 16) sB0[t] = b0[t];
    if (t < 8){ sB1[t] = b1[t]; sW2[t] = w2[t]; }

    // XCD-aware swizzle: with round-robin dispatch, each XCD gets a contiguous
    // 288-block (48-row) pixel strip -> featT tap neighborhoods stay in its L2.
    const int nb   = gridDim.x;             // 2304
    const int strip = nb >> 3;              // 288
    const int bid  = blockIdx.x;
    const int sid  = (bid & 7) * strip + (bid >> 3);
    const int blockBase = sid * 64;

    // cooperative coalesced stage of ref (view0 fp32) and depths for 64 pixels
    {
        const float* srcR = feat + blockBase;
        #pragma unroll
        for (int k=0;k<8;k++){
            const int i  = k*256 + t;
            const int c  = i >> 6;
            const int px = i & 63;
            sRef[px*33 + c] = srcR[(size_t)c*HWn + px];
        }
        const int dp = t >> 6;          // 0..3
        const int px = t & 63;
        sDep[dp*65 + px] = depths[(size_t)dp*HWn + blockBase + px];
    }

    if (t == 0){
        sB2s[0] = b2[0];
        // fold projection chain: uvd = A_s * (x,y,1) * depth + c_s
        float K0inv[9]; inv3(Kin, K0inv);
        float R0[9], t0[3];
        #pragma unroll
        for (int r=0;r<3;r++){
            #pragma unroll
            for (int c=0;c<3;c++) R0[r*3+c] = Ein[r*4+c];
            t0[r] = Ein[r*4+3];
        }
        float R0inv[9]; inv3(R0, R0inv);
        float M0[9]; mm3(R0inv, K0inv, M0);
        float Rt0[3]; mv3(R0inv, t0, Rt0);
        for (int s=1;s<Vn;s++){
            const float* Ks = Kin + s*9;
            const float* Es = Ein + s*12;
            float Rs[9], ts[3];
            #pragma unroll
            for (int r=0;r<3;r++){
                #pragma unroll
                for (int c=0;c<3;c++) Rs[r*3+c] = Es[r*4+c];
                ts[r] = Es[r*4+3];
            }
            float T1[9]; mm3(Rs, M0, T1);
            float A[9];  mm3(Ks, T1, A);
            float Rr[3]; mv3(Rs, Rt0, Rr);
            float tv[3] = { ts[0]-Rr[0], ts[1]-Rr[1], ts[2]-Rr[2] };
            float cv[3]; mv3(Ks, tv, cv);
            float* dm = &sM[(s-1)*12];
            #pragma unroll
            for (int i=0;i<9;i++) dm[i] = A[i];
            #pragma unroll
            for (int i=0;i<3;i++) dm[9+i] = cv[i];
        }
    }
    __syncthreads();

    const int pixLocal = t >> 2;        // 0..63
    const int s        = t & 3;         // source view index (0..3 -> view s+1)
    const int pix      = blockBase + pixLocal;
    const float xg = (float)(pix % Wn) + 0.5f;
    const float yg = (float)(pix / Wn) + 0.5f;

    // ref as 16 packed half2 (f16 precision > bf16 for N(0,1) data)
    h2 r2[16];
    #pragma unroll
    for (int k=0;k<16;k++){
        r2[k].x = (_Float16)sRef[pixLocal*33 + 2*k];
        r2[k].y = (_Float16)sRef[pixLocal*33 + 2*k+1];
    }
    float dep[Dn];
    #pragma unroll
    for (int d=0;d<Dn;d++) dep[d] = sDep[d*65 + pixLocal];

    const float* M = &sM[s*12];
    const float bx = M[0]*xg + M[1]*yg + M[2];
    const float by = M[3]*xg + M[4]*yg + M[5];
    const float bz = M[6]*xg + M[7]*yg + M[8];
    const float cx = M[9], cy = M[10], cz = M[11];
    const unsigned short* vbase = featT + (size_t)s*HWn*Cn;

    // one depth's taps -> sim[.][d_]
    auto depth_taps = [&](int d_, float* simcol){
        const float dd = dep[d_];
        const float ux = fmaf(bx, dd, cx);
        const float uy = fmaf(by, dd, cy);
        const float uz = fmaf(bz, dd, cz) + 1e-9f;
        const float rz = 1.f/uz;
        const float px = ux*rz, py = uy*rz;
        const float x0 = floorf(px), y0 = floorf(py);
        const float wx1 = px - x0, wy1 = py - y0;
        const float wx0 = 1.f - wx1, wy0 = 1.f - wy1;
        const bool vx0 = (x0 >= 0.f)     && (x0 <= (float)(Wn-1));
        const bool vx1 = (x0 >= -1.f)    && (x0 <= (float)(Wn-2));
        const bool vy0 = (y0 >= 0.f)     && (y0 <= (float)(Hn-1));
        const bool vy1 = (y0 >= -1.f)    && (y0 <= (float)(Hn-2));
        // fold the 1/4 group-mean into the tap weights
        const float w00 = (vx0&&vy0) ? 0.25f*wx0*wy0 : 0.f;
        const float w10 = (vx1&&vy0) ? 0.25f*wx1*wy0 : 0.f;
        const float w01 = (vx0&&vy1) ? 0.25f*wx0*wy1 : 0.f;
        const float w11 = (vx1&&vy1) ? 0.25f*wx1*wy1 : 0.f;
        // clamped integer coords (always safe to load)
        const int xi0 = (int)fminf(fmaxf(x0,     0.f), (float)(Wn-1));
        const int xi1 = (int)fminf(fmaxf(x0+1.f, 0.f), (float)(Wn-1));
        const int yi0 = (int)fminf(fmaxf(y0,     0.f), (float)(Hn-1));
        const int yi1 = (int)fminf(fmaxf(y0+1.f, 0.f), (float)(Hn-1));

        float sg[Gn];
        #pragma unroll
        for (int g=0; g<Gn; g++) sg[g] = 0.f;
        tap_f16(vbase, xi0, yi0, w00, r2, sg);
        tap_f16(vbase, xi1, yi0, w10, r2, sg);
        tap_f16(vbase, xi0, yi1, w01, r2, sg);
        tap_f16(vbase, xi1, yi1, w11, r2, sg);
        #pragma unroll
        for (int g=0; g<Gn; g++) simcol[g*Dn] = sg[g];
    };

    // depth-pair interleave: pair dp's MLP VALU work sits between the load
    // batches of pair dp and pair dp+1 -> latency hiding.
    float sim[Gn][Dn];
    float maxlog = -3.0e38f;
    #pragma unroll
    for (int dp=0; dp<2; dp++){
        const int d0 = 2*dp, d1 = 2*dp+1;
        depth_taps(d0, &sim[0][d0]);
        depth_taps(d1, &sim[0][d1]);
        // paired MLP over (d0,d1); max(sigmoid) == sigmoid(max logit)
        float hx[16], hy[16];
        #pragma unroll
        for (int o=0;o<16;o++){
            float ax = sB0[o], ay = sB0[o];
            #pragma unroll
            for (int g=0; g<Gn; g++){
                const float wv = sW0[o*Gn+g];
                ax = fmaf(wv, sim[g][d0], ax);
                ay = fmaf(wv, sim[g][d1], ay);
            }
            hx[o] = fmaxf(ax, 0.f);
            hy[o] = fmaxf(ay, 0.f);
        }
        float lgx = sB2s[0], lgy = sB2s[0];
        #pragma unroll
        for (int o=0;o<8;o++){
            float ax = sB1[o], ay = sB1[o];
            #pragma unroll
            for (int i=0;i<16;i++){
                const float wv = sW1[o*16+i];
                ax = fmaf(wv, hx[i], ax);
                ay = fmaf(wv, hy[i], ay);
            }
            const float w2v = sW2[o];
            lgx = fmaf(w2v, fmaxf(ax, 0.f), lgx);
            lgy = fmaf(w2v, fmaxf(ay, 0.f), lgy);
        }
        maxlog = fmaxf(maxlog, fmaxf(lgx, lgy));
    }
    const float vw = 1.f/(1.f + __expf(-maxlog));

    // scale by vw, butterfly-reduce across the 4 view lanes
    float wsum = vw;
    wsum += __shfl_xor(wsum, 1);
    wsum += __shfl_xor(wsum, 2);
    #pragma unroll
    for (int g=0;g<Gn;g++)
        #pragma unroll
        for (int d=0;d<Dn;d++){
            float v = sim[g][d]*vw;
            v += __shfl_xor(v, 1);
            v += __shfl_xor(v, 2);
            sim[g][d] = v;
        }

    if (s == 0){
        const float invw = 1.f/wsum;
        #pragma unroll
        for (int g=0;g<Gn;g++)
            #pragma unroll
            for (int d=0;d<Dn;d++)
                sOut[pixLocal*33 + g*Dn + d] = sim[g][d]*invw;
    }
    __syncthreads();

    // coalesced write-out: 32 planes x 64 pixels
    float* oBase = out + blockBase;
    #pragma unroll
    for (int k=0;k<8;k++){
        const int e     = k*256 + t;
        const int plane = e >> 6;
        const int pixel = e & 63;
        oBase[(size_t)plane*HWn + pixel] = sOut[pixel*33 + plane];
    }
}

extern "C" void kernel_launch(void* const* d_in, const int* in_sizes, int n_in,
                              void* d_out, int out_size, void* d_ws, size_t ws_size,
                              hipStream_t stream)
{
    (void)in_sizes; (void)n_in; (void)out_size; (void)ws_size;
    const float* feat   = (const float*)d_in[0];
    const float* depths = (const float*)d_in[1];
    const float* K      = (const float*)d_in[2];
    const float* E      = (const float*)d_in[3];
    const float* w0     = (const float*)d_in[4];
    const float* b0     = (const float*)d_in[5];
    const float* w1     = (const float*)d_in[6];
    const float* b1     = (const float*)d_in[7];
    const float* w2     = (const float*)d_in[8];
    const float* b2     = (const float*)d_in[9];
    float* out = (float*)d_out;
    unsigned short* featT = (unsigned short*)d_ws;   // (V-1, HW, C) f16 = 37.7 MB

    dim3 g(HWn/256, Vn-1);
    transpose_kernel<<<g, 256, 0, stream>>>(feat, featT);
    gbinet_kernel<<<HWn/64, 256, 0, stream>>>(feat, depths, K, E,
                                              w0,b0,w1,b1,w2,b2, featT, out);
}

// Round 9
// 237.347 us; speedup vs baseline: 1.4450x; 1.4450x over previous
//
#include <hip/hip_runtime.h>
#include <math.h>

#define Vn 5
#define Cn 32
#define Hn 384
#define Wn 384
#define Dn 4
#define Gn 8
#define HWn (Hn*Wn)   // 147456

typedef _Float16 h2 __attribute__((ext_vector_type(2)));

__device__ __forceinline__ float fdot2h(h2 a, h2 b, float c){
#if __has_builtin(__builtin_amdgcn_fdot2)
    return __builtin_amdgcn_fdot2(a, b, c, false);
#else
    return (float)a.x*(float)b.x + (float)a.y*(float)b.y + c;
#endif
}
__device__ __forceinline__ unsigned int packh2(float a, float b){  // accurate pack (RNE)
    h2 h;
    h.x = (_Float16)a;
    h.y = (_Float16)b;
    return __builtin_bit_cast(unsigned int, h);
}

// ---------- small 3x3 helpers (device) ----------
__device__ __forceinline__ void inv3(const float* m, float* o){
    float a=m[0],b=m[1],c=m[2],d=m[3],e=m[4],f=m[5],g=m[6],h=m[7],i=m[8];
    float A =  e*i - f*h;
    float B = -(d*i - f*g);
    float C =  d*h - e*g;
    float det = a*A + b*B + c*C;
    float r = 1.f/det;
    o[0] = A*r;            o[1] = -(b*i - c*h)*r;  o[2] =  (b*f - c*e)*r;
    o[3] = B*r;            o[4] =  (a*i - c*g)*r;  o[5] = -(a*f - c*d)*r;
    o[6] = C*r;            o[7] = -(a*h - b*g)*r;  o[8] =  (a*e - b*d)*r;
}
__device__ __forceinline__ void mm3(const float* a, const float* b, float* o){
    #pragma unroll
    for (int r=0;r<3;r++)
        #pragma unroll
        for (int c=0;c<3;c++)
            o[r*3+c] = a[r*3+0]*b[0*3+c] + a[r*3+1]*b[1*3+c] + a[r*3+2]*b[2*3+c];
}
__device__ __forceinline__ void mv3(const float* a, const float* v, float* o){
    #pragma unroll
    for (int r=0;r<3;r++)
        o[r] = a[r*3+0]*v[0] + a[r*3+1]*v[1] + a[r*3+2]*v[2];
}

// ---------- transpose+convert source views (C,H,W) fp32 -> (H*W, C) f16 ----------
__global__ __launch_bounds__(256)
void transpose_kernel(const float* __restrict__ feat, unsigned short* __restrict__ featT){
    __shared__ float tile[32][257];
    const int s  = blockIdx.y;            // 0..3 -> view s+1
    const int p0 = blockIdx.x * 256;      // pixel tile base
    const int t  = threadIdx.x;
    const float* src = feat + (size_t)(s+1)*Cn*HWn + p0;
    #pragma unroll
    for (int k=0;k<8;k++){
        const int i   = k*256 + t;
        const int px4 = (i & 63) * 4;
        const int ch  = i >> 6;
        const float4 v = *(const float4*)(src + (size_t)ch*HWn + px4);
        tile[ch][px4+0]=v.x; tile[ch][px4+1]=v.y; tile[ch][px4+2]=v.z; tile[ch][px4+3]=v.w;
    }
    __syncthreads();
    uint4* dst = (uint4*)(featT + ((size_t)s*HWn + p0 + t)*Cn);
    #pragma unroll
    for (int q=0;q<4;q++){
        uint4 o;
        o.x = packh2(tile[8*q+0][t], tile[8*q+1][t]);
        o.y = packh2(tile[8*q+2][t], tile[8*q+3][t]);
        o.z = packh2(tile[8*q+4][t], tile[8*q+5][t]);
        o.w = packh2(tile[8*q+6][t], tile[8*q+7][t]);
        dst[q] = o;
    }
}

// one group (4 ch = 2 half2): two v_dot2_f32_f16 + one fma
#define DOTG(uA, uB, g)                                                        \
    {                                                                          \
        const h2 pa = __builtin_bit_cast(h2, (uA));                            \
        const h2 pb = __builtin_bit_cast(h2, (uB));                            \
        const float dt = fdot2h(pa, r2[2*(g)], fdot2h(pb, r2[2*(g)+1], 0.f));  \
        sg[(g)] = fmaf(w, dt, sg[(g)]);                                        \
    }

// guarded bilinear tap: loads only if weight nonzero, immediate consume
__device__ __forceinline__ void tap_f16(const unsigned short* __restrict__ vbase,
                                        int xc, int yc, float w,
                                        const h2* r2, float* sg)
{
    if (w != 0.f){
        const uint4* p = (const uint4*)(vbase + ((size_t)yc*Wn + xc)*Cn);
        const uint4 q0 = p[0];
        const uint4 q1 = p[1];
        const uint4 q2 = p[2];
        const uint4 q3 = p[3];
        DOTG(q0.x, q0.y, 0)
        DOTG(q0.z, q0.w, 1)
        DOTG(q1.x, q1.y, 2)
        DOTG(q1.z, q1.w, 3)
        DOTG(q2.x, q2.y, 4)
        DOTG(q2.z, q2.w, 5)
        DOTG(q3.x, q3.y, 6)
        DOTG(q3.z, q3.w, 7)
    }
}

// ---------- fused main kernel: one thread per (pixel, source view) ----------
// Block = 256 threads = 64 pixels x 4 views; 4 view-lanes adjacent -> shfl_xor.
// launch_bounds(256,2): empirical VGPR cap 128 (cap 64 at arg=4 caused 1.6GB
// of scratch spill traffic in R4 -- this kernel needs ~100 VGPRs).
// NOTE: sim/sg/acc must ONLY be accessed with compile-time indices -- passing
// a pointer into a local array (R8) or indexed uint4 aggregates (R3) defeats
// SROA and spills everything to scratch (0.5-2 GB of HBM traffic).
__global__ __launch_bounds__(256, 2)
void gbinet_kernel(const float* __restrict__ feat,
                   const float* __restrict__ depths,
                   const float* __restrict__ Kin,
                   const float* __restrict__ Ein,
                   const float* __restrict__ w0, const float* __restrict__ b0,
                   const float* __restrict__ w1, const float* __restrict__ b1,
                   const float* __restrict__ w2, const float* __restrict__ b2,
                   const unsigned short* __restrict__ featT,
                   float* __restrict__ out)
{
    __shared__ float sW0[128], sW1[128], sB0[16], sB1[8], sW2[8], sB2s[1];
    __shared__ float sM[48];            // per source view: A[9] + c[3]
    __shared__ float sRef[64*33];       // 64 pixels x 32 ref channels (pad 33)
    __shared__ float sDep[4*65];        // 4 depth planes x 64 pixels (pad 65)
    __shared__ float sOut[64*33];       // 64 pixels x 32 outputs (pad 33)
    const int t = threadIdx.x;
    if (t < 128){ sW0[t] = w0[t]; sW1[t] = w1[t]; }
    if (t < 16) sB0[t] = b0[t];
    if (t < 8){ sB1[t] = b1[t]; sW2[t] = w2[t]; }

    // XCD swizzle: round-robin dispatch -> each XCD gets a contiguous 288-block
    // (48-row) strip; featT tap neighborhoods stay in its private 4MB L2.
    const int bid = blockIdx.x;
    const int sid = (bid & 7) * (HWn/64/8) + (bid >> 3);
    const int blockBase = sid * 64;

    // cooperative coalesced stage of ref (view0 fp32) and depths for 64 pixels
    {
        const float* srcR = feat + blockBase;
        #pragma unroll
        for (int k=0;k<8;k++){
            const int i  = k*256 + t;
            const int c  = i >> 6;
            const int px = i & 63;
            sRef[px*33 + c] = srcR[(size_t)c*HWn + px];
        }
        const int dp = t >> 6;          // 0..3
        const int px = t & 63;
        sDep[dp*65 + px] = depths[(size_t)dp*HWn + blockBase + px];
    }

    if (t == 0){
        sB2s[0] = b2[0];
        // fold projection chain: uvd = A_s * (x,y,1) * depth + c_s
        float K0inv[9]; inv3(Kin, K0inv);
        float R0[9], t0[3];
        #pragma unroll
        for (int r=0;r<3;r++){
            #pragma unroll
            for (int c=0;c<3;c++) R0[r*3+c] = Ein[r*4+c];
            t0[r] = Ein[r*4+3];
        }
        float R0inv[9]; inv3(R0, R0inv);
        float M0[9]; mm3(R0inv, K0inv, M0);
        float Rt0[3]; mv3(R0inv, t0, Rt0);
        for (int s=1;s<Vn;s++){
            const float* Ks = Kin + s*9;
            const float* Es = Ein + s*12;
            float Rs[9], ts[3];
            #pragma unroll
            for (int r=0;r<3;r++){
                #pragma unroll
                for (int c=0;c<3;c++) Rs[r*3+c] = Es[r*4+c];
                ts[r] = Es[r*4+3];
            }
            float T1[9]; mm3(Rs, M0, T1);
            float A[9];  mm3(Ks, T1, A);
            float Rr[3]; mv3(Rs, Rt0, Rr);
            float tv[3] = { ts[0]-Rr[0], ts[1]-Rr[1], ts[2]-Rr[2] };
            float cv[3]; mv3(Ks, tv, cv);
            float* dm = &sM[(s-1)*12];
            #pragma unroll
            for (int i=0;i<9;i++) dm[i] = A[i];
            #pragma unroll
            for (int i=0;i<3;i++) dm[9+i] = cv[i];
        }
    }
    __syncthreads();

    const int pixLocal = t >> 2;        // 0..63
    const int s        = t & 3;         // source view index (0..3 -> view s+1)
    const int pix      = blockBase + pixLocal;
    const float xg = (float)(pix % Wn) + 0.5f;
    const float yg = (float)(pix / Wn) + 0.5f;

    // ref as 16 packed half2 (f16 precision > bf16 for N(0,1) data)
    h2 r2[16];
    #pragma unroll
    for (int k=0;k<16;k++){
        r2[k].x = (_Float16)sRef[pixLocal*33 + 2*k];
        r2[k].y = (_Float16)sRef[pixLocal*33 + 2*k+1];
    }
    float dep[Dn];
    #pragma unroll
    for (int d=0;d<Dn;d++) dep[d] = sDep[d*65 + pixLocal];

    const float* M = &sM[s*12];
    const float bx = M[0]*xg + M[1]*yg + M[2];
    const float by = M[3]*xg + M[4]*yg + M[5];
    const float bz = M[6]*xg + M[7]*yg + M[8];
    const float cx = M[9], cy = M[10], cz = M[11];
    const unsigned short* vbase = featT + (size_t)s*HWn*Cn;

    float sim[Gn][Dn];
    #pragma unroll
    for (int d=0;d<Dn;d++){
        const float dd = dep[d];
        const float ux = fmaf(bx, dd, cx);
        const float uy = fmaf(by, dd, cy);
        const float uz = fmaf(bz, dd, cz) + 1e-9f;
        const float rz = 1.f/uz;
        const float px = ux*rz, py = uy*rz;
        const float x0 = floorf(px), y0 = floorf(py);
        const float wx1 = px - x0, wy1 = py - y0;
        const float wx0 = 1.f - wx1, wy0 = 1.f - wy1;
        const bool vx0 = (x0 >= 0.f)     && (x0 <= (float)(Wn-1));
        const bool vx1 = (x0 >= -1.f)    && (x0 <= (float)(Wn-2));
        const bool vy0 = (y0 >= 0.f)     && (y0 <= (float)(Hn-1));
        const bool vy1 = (y0 >= -1.f)    && (y0 <= (float)(Hn-2));
        // fold the 1/4 group-mean into the tap weights
        const float w00 = (vx0&&vy0) ? 0.25f*wx0*wy0 : 0.f;
        const float w10 = (vx1&&vy0) ? 0.25f*wx1*wy0 : 0.f;
        const float w01 = (vx0&&vy1) ? 0.25f*wx0*wy1 : 0.f;
        const float w11 = (vx1&&vy1) ? 0.25f*wx1*wy1 : 0.f;
        // clamped integer coords (always safe to load)
        const int xi0 = (int)fminf(fmaxf(x0,     0.f), (float)(Wn-1));
        const int xi1 = (int)fminf(fmaxf(x0+1.f, 0.f), (float)(Wn-1));
        const int yi0 = (int)fminf(fmaxf(y0,     0.f), (float)(Hn-1));
        const int yi1 = (int)fminf(fmaxf(y0+1.f, 0.f), (float)(Hn-1));

        float sg[Gn];
        #pragma unroll
        for (int g=0; g<Gn; g++) sg[g] = 0.f;
        tap_f16(vbase, xi0, yi0, w00, r2, sg);
        tap_f16(vbase, xi1, yi0, w10, r2, sg);
        tap_f16(vbase, xi0, yi1, w01, r2, sg);
        tap_f16(vbase, xi1, yi1, w11, r2, sg);
        #pragma unroll
        for (int g=0; g<Gn; g++) sim[g][d] = sg[g];
    }

    // pixelwise net over 4 depths, two depths at a time (v_pk_fma_f32 pairs);
    // max(sigmoid) == sigmoid(max logit)
    float maxlog = -3.0e38f;
    #pragma unroll
    for (int dp=0; dp<2; dp++){
        const int d0 = 2*dp, d1 = 2*dp+1;
        float hx[16], hy[16];
        #pragma unroll
        for (int o=0;o<16;o++){
            float ax = sB0[o], ay = sB0[o];
            #pragma unroll
            for (int g=0; g<Gn; g++){
                const float wv = sW0[o*Gn+g];
                ax = fmaf(wv, sim[g][d0], ax);
                ay = fmaf(wv, sim[g][d1], ay);
            }
            hx[o] = fmaxf(ax, 0.f);
            hy[o] = fmaxf(ay, 0.f);
        }
        float lgx = sB2s[0], lgy = sB2s[0];
        #pragma unroll
        for (int o=0;o<8;o++){
            float ax = sB1[o], ay = sB1[o];
            #pragma unroll
            for (int i=0;i<16;i++){
                const float wv = sW1[o*16+i];
                ax = fmaf(wv, hx[i], ax);
                ay = fmaf(wv, hy[i], ay);
            }
            const float w2v = sW2[o];
            lgx = fmaf(w2v, fmaxf(ax, 0.f), lgx);
            lgy = fmaf(w2v, fmaxf(ay, 0.f), lgy);
        }
        maxlog = fmaxf(maxlog, fmaxf(lgx, lgy));
    }
    const float vw = 1.f/(1.f + __expf(-maxlog));

    // scale by vw, butterfly-reduce across the 4 view lanes
    float wsum = vw;
    wsum += __shfl_xor(wsum, 1);
    wsum += __shfl_xor(wsum, 2);
    #pragma unroll
    for (int g=0;g<Gn;g++)
        #pragma unroll
        for (int d=0;d<Dn;d++){
            float v = sim[g][d]*vw;
            v += __shfl_xor(v, 1);
            v += __shfl_xor(v, 2);
            sim[g][d] = v;
        }

    if (s == 0){
        const float invw = 1.f/wsum;
        #pragma unroll
        for (int g=0;g<Gn;g++)
            #pragma unroll
            for (int d=0;d<Dn;d++)
                sOut[pixLocal*33 + g*Dn + d] = sim[g][d]*invw;
    }
    __syncthreads();

    // coalesced write-out: 32 planes x 64 pixels
    float* oBase = out + blockBase;
    #pragma unroll
    for (int k=0;k<8;k++){
        const int e     = k*256 + t;
        const int plane = e >> 6;
        const int pixel = e & 63;
        oBase[(size_t)plane*HWn + pixel] = sOut[pixel*33 + plane];
    }
}

extern "C" void kernel_launch(void* const* d_in, const int* in_sizes, int n_in,
                              void* d_out, int out_size, void* d_ws, size_t ws_size,
                              hipStream_t stream)
{
    (void)in_sizes; (void)n_in; (void)out_size; (void)ws_size;
    const float* feat   = (const float*)d_in[0];
    const float* depths = (const float*)d_in[1];
    const float* K      = (const float*)d_in[2];
    const float* E      = (const float*)d_in[3];
    const float* w0     = (const float*)d_in[4];
    const float* b0     = (const float*)d_in[5];
    const float* w1     = (const float*)d_in[6];
    const float* b1     = (const float*)d_in[7];
    const float* w2     = (const float*)d_in[8];
    const float* b2     = (const float*)d_in[9];
    float* out = (float*)d_out;
    unsigned short* featT = (unsigned short*)d_ws;   // (V-1, HW, C) f16 = 37.7 MB

    dim3 g(HWn/256, Vn-1);
    transpose_kernel<<<g, 256, 0, stream>>>(feat, featT);
    gbinet_kernel<<<HWn/64, 256, 0, stream>>>(feat, depths, K, E,
                                              w0,b0,w1,b1,w2,b2, featT, out);
}